// Round 5
// baseline (735.807 us; speedup 1.0000x reference)
//
#include <hip/hip_runtime.h>
#include <cstdint>
#include <cstddef>

typedef unsigned short u16;
using bf16x8  = __attribute__((ext_vector_type(8))) short;
using floatx4 = __attribute__((ext_vector_type(4))) float;

// ---------- helpers ----------
__device__ __forceinline__ u16 f2bf(float f) {
    union { float f; unsigned u; } v; v.f = f;
    unsigned r = v.u + 0x7fffu + ((v.u >> 16) & 1u);   // RNE
    return (u16)(r >> 16);
}
__device__ __forceinline__ float bf2f(u16 h) {
    union { unsigned u; float f; } v; v.u = ((unsigned)h) << 16; return v.f;
}
__device__ __forceinline__ floatx4 mfma16(bf16x8 a, bf16x8 b, floatx4 c) {
    return __builtin_amdgcn_mfma_f32_16x16x32_bf16(a, b, c, 0, 0, 0);
}
using gptr_t = const __attribute__((address_space(1))) unsigned int*;
using lptr_t = __attribute__((address_space(3))) unsigned int*;
__device__ __forceinline__ void lds16(const void* g, void* l) {
    __builtin_amdgcn_global_load_lds((gptr_t)g, (lptr_t)l, 16, 0, 0);
}
// Inline-asm ds_read_b128: invisible to SIInsertWaitcnts, so the compiler cannot
// inject a conservative vmcnt(0) drain against outstanding global_load_lds (LDS-DMA).
typedef __attribute__((address_space(3))) const u16* lds_cp;
__device__ __forceinline__ bf16x8 dsr128(const u16* p) {
    bf16x8 r;
    asm volatile("ds_read_b128 %0, %1" : "=v"(r) : "v"((lds_cp)p));
    return r;
}

#define ATT_SCALE 0.1275758218522532f   // log2(e) / sqrt(128)

// ---------- 1. convert x f32 -> bf16 ----------
__global__ __launch_bounds__(256) void cvt_x(const float* __restrict__ x, u16* __restrict__ xb) {
    size_t i = ((size_t)blockIdx.x * 256 + threadIdx.x) * 4;
    float4 v = *(const float4*)&x[i];
    ushort4 r; r.x = f2bf(v.x); r.y = f2bf(v.y); r.z = f2bf(v.z); r.w = f2bf(v.w);
    *(ushort4*)&xb[i] = r;
}

// ---------- 2. transpose+convert all 4 weights f32 [2048][2048] -> bf16 [n][k] ----------
__global__ __launch_bounds__(256) void transpose_wall(const float* __restrict__ wq, const float* __restrict__ wk,
                                                      const float* __restrict__ wv, const float* __restrict__ wo,
                                                      u16* __restrict__ wqkvb, u16* __restrict__ wob) {
    __shared__ float t[64][65];
    const int z = blockIdx.z;
    const float* in = (z == 0) ? wq : (z == 1) ? wk : (z == 2) ? wv : wo;
    u16* out = (z < 3) ? (wqkvb + (size_t)z * 2048 * 2048) : wob;
    int k0 = blockIdx.x * 64, n0 = blockIdx.y * 64;
    int tx = threadIdx.x, ty = threadIdx.y;   // (64,4)
#pragma unroll
    for (int i = 0; i < 16; ++i) {
        int r = i * 4 + ty;
        t[r][tx] = in[(size_t)(k0 + r) * 2048 + n0 + tx];
    }
    __syncthreads();
#pragma unroll
    for (int i = 0; i < 16; ++i) {
        int r = i * 4 + ty;
        out[(size_t)(n0 + r) * 2048 + k0 + tx] = f2bf(t[tx][r]);
    }
}

// ---------- 3. main GEMM: 256x256 tile, BK=64, 8 waves, 8-phase pipelined (T1..T5) ----------
// (unchanged from round 4: inline-asm ds_read + explicit waits, counted vmcnt(4) per K-tile,
//  rope-pair wave->column remap, fused RoPE epilogue on MODE 0.)
template <int MODE>
__global__ __launch_bounds__(512, 2) void gemm_bt(const u16* __restrict__ A, const u16* __restrict__ B,
                                                  u16* __restrict__ Qo, u16* __restrict__ Ko, u16* __restrict__ Vt,
                                                  float* __restrict__ Co,
                                                  const float* __restrict__ cosb, const float* __restrict__ sinb) {
    __shared__ __align__(16) u16 sA[2][16384];   // [buf][256 rows][64] 64 KiB
    __shared__ __align__(16) u16 sB[2][16384];   // 64 KiB -> 128 KiB total, 1 block/CU

    const int nbx = (MODE == 0) ? 24 : 8;
    const int bid = blockIdx.x;
    const int q8 = (int)gridDim.x >> 3;
    const int wg = (bid & 7) * q8 + (bid >> 3);
    const int bx = wg % nbx, by = wg / nbx;
    const int m0 = by << 8, n0 = bx << 8;

    const int tid = threadIdx.x;
    const int w = tid >> 6, lane = tid & 63;
    const int wm = w >> 2, wn = w & 3;              // 2 (M) x 4 (N) waves
    const int m16 = lane & 15, q4 = lane >> 4;
    const int lr = lane >> 3;
    const int lc8 = (lane & 7) ^ lr;                // pre-swizzled source chunk
    const int wnbase = (wn >> 1) * 128 + (wn & 1) * 32;   // rope-pair column base

    const u16* Ag = A + (size_t)(m0 + w * 16 + lr) * 2048 + lc8 * 8;
    const u16* Bg = B + (size_t)(n0 + w * 16 + lr) * 2048 + lc8 * 8;

    const int swz0 = ((q4 ^ (m16 & 7)) << 3);
    const int swz1 = (((4 + q4) ^ (m16 & 7)) << 3);

    floatx4 acc[8][4];
#pragma unroll
    for (int r = 0; r < 8; ++r)
#pragma unroll
        for (int c = 0; c < 4; ++c) acc[r][c] = (floatx4)0.0f;
    bf16x8 af[4][2];
    bf16x8 bf[4][2];

#define STAGE_A(b, h, t) do { \
    lds16(Ag + (size_t)((h) * 128) * 2048 + (t) * 64,     &sA[b][(h) * 8192 + w * 1024]);       \
    lds16(Ag + (size_t)((h) * 128 + 8) * 2048 + (t) * 64, &sA[b][(h) * 8192 + w * 1024 + 512]); \
} while (0)
#define STAGE_B(b, h, t) do { \
    lds16(Bg + (size_t)((h) * 128) * 2048 + (t) * 64,     &sB[b][(h) * 8192 + w * 1024]);       \
    lds16(Bg + (size_t)((h) * 128 + 8) * 2048 + (t) * 64, &sB[b][(h) * 8192 + w * 1024 + 512]); \
} while (0)
#define BAR() __builtin_amdgcn_s_barrier()
#define WAITL0() do { asm volatile("s_waitcnt lgkmcnt(0)" ::: "memory"); __builtin_amdgcn_sched_barrier(0); } while (0)
#define WAITL8() asm volatile("s_waitcnt lgkmcnt(8)" ::: "memory")
#define LDA_(cur, mq) do { _Pragma("unroll") for (int fr = 0; fr < 4; ++fr) { \
    const u16* p = &sA[cur][(wm * 128 + (mq) * 64 + fr * 16 + m16) * 64];      \
    af[fr][0] = dsr128(&p[swz0]);                                              \
    af[fr][1] = dsr128(&p[swz1]); } } while (0)
#define LDB_(cur, nq) do { _Pragma("unroll") for (int c = 0; c < 2; ++c) {     \
    const int j = (nq) * 2 + c;                                                \
    const u16* p = &sB[cur][(wnbase + (j & 1) * 16 + (j >> 1) * 64 + m16) * 64]; \
    bf[j][0] = dsr128(&p[swz0]);                                               \
    bf[j][1] = dsr128(&p[swz1]); } } while (0)
#define MM_(mq, nq) do { _Pragma("unroll") for (int kk = 0; kk < 2; ++kk)      \
    _Pragma("unroll") for (int fr = 0; fr < 4; ++fr)                           \
    _Pragma("unroll") for (int c = 0; c < 2; ++c)                              \
        acc[(mq) * 4 + fr][(nq) * 2 + c] =                                     \
            mfma16(af[fr][kk], bf[(nq) * 2 + c][kk], acc[(mq) * 4 + fr][(nq) * 2 + c]); } while (0)

    const int NT = 32;   // K = 2048 / BK = 64

    STAGE_B(0, 0, 0); STAGE_B(0, 1, 0);
    STAGE_A(0, 0, 0); STAGE_A(0, 1, 0);
    STAGE_B(1, 0, 1); STAGE_B(1, 1, 1);
    asm volatile("s_waitcnt vmcnt(4)" ::: "memory");
    __builtin_amdgcn_s_barrier();

#pragma unroll 2
    for (int t = 0; t < NT; ++t) {
        const int cur = t & 1;
        // ---- P0 ----
        LDB_(cur, 0);
        LDA_(cur, 0);
        if (t + 1 < NT) STAGE_A(cur ^ 1, 0, t + 1);
        WAITL8();
        BAR();
        WAITL0();
        __builtin_amdgcn_s_setprio(1); MM_(0, 0); __builtin_amdgcn_s_setprio(0);
        BAR();
        // ---- P1 ----
        LDB_(cur, 1);
        if (t + 1 < NT) STAGE_A(cur ^ 1, 1, t + 1);
        BAR();
        WAITL0();
        __builtin_amdgcn_s_setprio(1); MM_(0, 1); __builtin_amdgcn_s_setprio(0);
        BAR();
        // ---- P2 ----
        LDA_(cur, 1);
        if (t + 2 < NT) STAGE_B(cur, 0, t + 2);
        BAR();
        WAITL0();
        __builtin_amdgcn_s_setprio(1); MM_(1, 1); __builtin_amdgcn_s_setprio(0);
        BAR();
        // ---- P3 ----
        if (t + 2 < NT) STAGE_B(cur, 1, t + 2);
        BAR();
        __builtin_amdgcn_s_setprio(1); MM_(1, 0); __builtin_amdgcn_s_setprio(0);
        if (t + 2 < NT)      { asm volatile("s_waitcnt vmcnt(4)" ::: "memory"); }
        else if (t + 1 < NT) { asm volatile("s_waitcnt vmcnt(0)" ::: "memory"); }
        BAR();
    }

#undef STAGE_A
#undef STAGE_B
#undef BAR
#undef WAITL0
#undef WAITL8
#undef LDA_
#undef LDB_
#undef MM_

    if (MODE == 0) {
        const int which = n0 >> 11;           // 0=Q 1=K 2=V
        if (which < 2) {
            u16* dst = (which == 0) ? Qo : Ko;
            const float sc = (which == 0) ? ATT_SCALE : 1.0f;
            const int h = ((n0 >> 7) + (wn >> 1)) & 15;
            const int dp0 = (wn & 1) * 32 + m16;
#pragma unroll
            for (int fr = 0; fr < 8; ++fr) {
                const int mb = m0 + wm * 128 + fr * 16 + q4 * 4;
#pragma unroll
                for (int c0 = 0; c0 < 2; ++c0) {
                    const int dp = dp0 + c0 * 16;
#pragma unroll
                    for (int i = 0; i < 4; ++i) {
                        const int mm = mb + i;
                        const int b = mm >> 11, s = mm & 2047;
                        const float cs = cosb[(size_t)s * 64 + dp];
                        const float sn = sinb[(size_t)s * 64 + dp];
                        const float lo = acc[fr][c0][i], hi = acc[fr][c0 + 2][i];
                        const size_t base = ((size_t)((b * 16 + h) * 2048 + s) << 7) + dp;
                        dst[base]      = f2bf((lo * cs - hi * sn) * sc);
                        dst[base + 64] = f2bf((hi * cs + lo * sn) * sc);
                    }
                }
            }
        } else {
#pragma unroll
            for (int fr = 0; fr < 8; ++fr) {
                const int mb = m0 + wm * 128 + fr * 16 + q4 * 4;
                const int b = mb >> 11, s = mb & 2047;
#pragma unroll
                for (int c = 0; c < 4; ++c) {
                    const int n = n0 + wnbase + (c & 1) * 16 + (c >> 1) * 64 + m16;
                    const int h = (n >> 7) & 15, d = n & 127;
                    ushort4 pk;
                    pk.x = f2bf(acc[fr][c][0]); pk.y = f2bf(acc[fr][c][1]);
                    pk.z = f2bf(acc[fr][c][2]); pk.w = f2bf(acc[fr][c][3]);
                    *(ushort4*)&Vt[((size_t)((b * 16 + h) * 128 + d)) * 2048 + s] = pk;
                }
            }
        }
    } else {
#pragma unroll
        for (int fr = 0; fr < 8; ++fr) {
            const int mb = m0 + wm * 128 + fr * 16 + q4 * 4;
#pragma unroll
            for (int c = 0; c < 4; ++c) {
                const int n = n0 + wnbase + (c & 1) * 16 + (c >> 1) * 64 + m16;
#pragma unroll
                for (int i = 0; i < 4; ++i)
                    Co[(size_t)(mb + i) * 2048 + n] = acc[fr][c][i];
            }
        }
    }
}

// ---------- 4. flash attention v6: NO K/V LDS staging, NO barriers in j-loop ----------
// K and V^T are read per-fragment directly from global: the 32KB tile is re-read by all
// 8 waves back-to-back -> L1/L2 hits; HBM traffic unchanged. Waves are fully independent
// (no __syncthreads at all), so MFMA / VALU / VMEM pipes overlap across waves and
// s_setprio arbitration pays (m191 regime). V fragments are prefetched into registers
// BEFORE the softmax so ~500 cyc of VALU hides their latency. Only the wave-private P
// rearrange buffer stays in LDS (same-wave ds ordering: compiler-inserted lgkmcnt).
__global__ __launch_bounds__(512, 2) void attn_kernel(const u16* __restrict__ Q, const u16* __restrict__ K,
                                                      const u16* __restrict__ VT, u16* __restrict__ AO) {
    __shared__ __align__(16) u16 ps[256 * 72];    // P  [q 256][k 64+8]
    static const int iqmap[8] = {7, 6, 5, 4, 0, 1, 2, 3};  // (bx, bx+256) pairs balance
    const int bx = blockIdx.x;
    const int iq = iqmap[bx >> 6];
    const int bh = bx & 63;
    const int b = bh >> 4, h = bh & 15;
    const u16* Qg = Q  + (size_t)bh * (2048 * 128);
    const u16* Kg = K  + (size_t)bh * (2048 * 128);
    const u16* Vg = VT + (size_t)bh * (128 * 2048);
    const int tid = threadIdx.x, w = tid >> 6, lane = tid & 63;
    const int m16 = lane & 15, q4 = lane >> 4;
    const int jn = 4 * iq + 4;

    const int qrow = iq * 256 + w * 32;
    bf16x8 qf[2][4];
#pragma unroll
    for (int rm = 0; rm < 2; ++rm)
#pragma unroll
        for (int kk = 0; kk < 4; ++kk)
            qf[rm][kk] = *(const bf16x8*)&Qg[(size_t)(qrow + rm * 16 + m16) * 128 + kk * 32 + q4 * 8];

    floatx4 o[2][8];
#pragma unroll
    for (int rm = 0; rm < 2; ++rm)
#pragma unroll
        for (int c = 0; c < 8; ++c) o[rm][c] = (floatx4)0.0f;
    float mrow[2] = {-1e30f, -1e30f}, lrow[2] = {0.0f, 0.0f};

    for (int j = 0; j < jn; ++j) {
        // ---- S^T = K Q^T, K fragments straight from global (L1-hot across 8 waves) ----
        floatx4 sacc[2][4];
#pragma unroll
        for (int rm = 0; rm < 2; ++rm)
#pragma unroll
            for (int r = 0; r < 4; ++r) sacc[rm][r] = (floatx4)0.0f;
#pragma unroll
        for (int kk = 0; kk < 4; ++kk) {
            bf16x8 kb[4];
#pragma unroll
            for (int r = 0; r < 4; ++r)
                kb[r] = *(const bf16x8*)&Kg[(size_t)(j * 64 + r * 16 + m16) * 128 + kk * 32 + q4 * 8];
            __builtin_amdgcn_s_setprio(1);
#pragma unroll
            for (int rm = 0; rm < 2; ++rm)
#pragma unroll
                for (int r = 0; r < 4; ++r)
                    sacc[rm][r] = mfma16(kb[r], qf[rm][kk], sacc[rm][r]);
            __builtin_amdgcn_s_setprio(0);
        }

        // ---- prefetch full V^T tile into regs: latency hidden under softmax VALU ----
        bf16x8 vb[2][8];
#pragma unroll
        for (int kk = 0; kk < 2; ++kk)
#pragma unroll
            for (int c8 = 0; c8 < 8; ++c8)
                vb[kk][c8] = *(const bf16x8*)&Vg[(size_t)(c8 * 16 + m16) * 2048 + j * 64 + kk * 32 + q4 * 8];

        // ---- causal mask ----
        if (j >= 4 * iq) {
#pragma unroll
            for (int rm = 0; rm < 2; ++rm) {
                const int qg = qrow + rm * 16 + m16;
#pragma unroll
                for (int r = 0; r < 4; ++r)
#pragma unroll
                    for (int i = 0; i < 4; ++i) {
                        int kg = j * 64 + r * 16 + q4 * 4 + i;
                        if (kg > qg) sacc[rm][r][i] = -1e30f;
                    }
            }
        }

        // ---- online softmax (lane-local along q, 4-lane groups along k) ----
#pragma unroll
        for (int rm = 0; rm < 2; ++rm) {
            float pmax = -1e30f;
#pragma unroll
            for (int r = 0; r < 4; ++r)
#pragma unroll
                for (int i = 0; i < 4; ++i) pmax = fmaxf(pmax, sacc[rm][r][i]);
            pmax = fmaxf(pmax, __shfl_xor(pmax, 16));
            pmax = fmaxf(pmax, __shfl_xor(pmax, 32));
            float mnew = fmaxf(mrow[rm], pmax);
            float alpha = __builtin_amdgcn_exp2f(mrow[rm] - mnew);
            mrow[rm] = mnew;

            float psum = 0.0f;
#pragma unroll
            for (int r = 0; r < 4; ++r) {
                float p0 = __builtin_amdgcn_exp2f(sacc[rm][r][0] - mnew);
                float p1 = __builtin_amdgcn_exp2f(sacc[rm][r][1] - mnew);
                float p2 = __builtin_amdgcn_exp2f(sacc[rm][r][2] - mnew);
                float p3 = __builtin_amdgcn_exp2f(sacc[rm][r][3] - mnew);
                psum += (p0 + p1) + (p2 + p3);
                ushort4 pk; pk.x = f2bf(p0); pk.y = f2bf(p1); pk.z = f2bf(p2); pk.w = f2bf(p3);
                *(ushort4*)&ps[(w * 32 + rm * 16 + m16) * 72 + r * 16 + q4 * 4] = pk;
            }
            psum += __shfl_xor(psum, 16);
            psum += __shfl_xor(psum, 32);
            lrow[rm] = lrow[rm] * alpha + psum;

            float abc[4];
#pragma unroll
            for (int i = 0; i < 4; ++i) abc[i] = __shfl(alpha, q4 * 4 + i);
#pragma unroll
            for (int c = 0; c < 8; ++c)
#pragma unroll
                for (int i = 0; i < 4; ++i) o[rm][c][i] *= abc[i];
        }

        // ---- O += P V : pa from wave-private LDS, V from registers ----
#pragma unroll
        for (int kk = 0; kk < 2; ++kk) {
            bf16x8 pa[2];
#pragma unroll
            for (int rm = 0; rm < 2; ++rm)
                pa[rm] = *(const bf16x8*)&ps[(w * 32 + rm * 16 + m16) * 72 + kk * 32 + q4 * 8];
            __builtin_amdgcn_s_setprio(1);
#pragma unroll
            for (int c8 = 0; c8 < 8; ++c8)
#pragma unroll
                for (int rm = 0; rm < 2; ++rm)
                    o[rm][c8] = mfma16(pa[rm], vb[kk][c8], o[rm][c8]);
            __builtin_amdgcn_s_setprio(0);
        }
    }

    // ---- epilogue ----
#pragma unroll
    for (int rm = 0; rm < 2; ++rm) {
        float linv = __builtin_amdgcn_rcpf(lrow[rm]);
        float li[4];
#pragma unroll
        for (int i = 0; i < 4; ++i) li[i] = __shfl(linv, q4 * 4 + i);
#pragma unroll
        for (int c = 0; c < 8; ++c)
#pragma unroll
            for (int i = 0; i < 4; ++i) {
                int s = qrow + rm * 16 + q4 * 4 + i;
                int d = c * 16 + m16;
                AO[((size_t)(b * 2048 + s)) * 2048 + h * 128 + d] = f2bf(o[rm][c][i] * li[i]);
            }
    }
}

// ---------- launch ----------
extern "C" void kernel_launch(void* const* d_in, const int* in_sizes, int n_in,
                              void* d_out, int out_size, void* d_ws, size_t ws_size,
                              hipStream_t stream) {
    const float* x    = (const float*)d_in[0];
    const float* wq   = (const float*)d_in[1];
    const float* wk   = (const float*)d_in[2];
    const float* wv   = (const float*)d_in[3];
    const float* wo   = (const float*)d_in[4];
    const float* cosb = (const float*)d_in[5];
    const float* sinb = (const float*)d_in[6];
    float* out = (float*)d_out;

    char* ws = (char*)d_ws;
    u16* xb    = (u16*)(ws);                          // 32 MiB
    u16* AO    = xb;                                  // alias: xb dead after QKV GEMM
    u16* wqkvb = (u16*)(ws + 33554432);               // 24 MiB
    u16* wob   = (u16*)(ws + 58720256);               // 8 MiB
    u16* Qb    = (u16*)(ws + 67108864);               // 32 MiB
    u16* Kb    = (u16*)(ws + 100663296);              // 32 MiB
    u16* Vtb   = (u16*)(ws + 134217728);              // 32 MiB (V stored transposed)

    cvt_x<<<16384, 256, 0, stream>>>(x, xb);
    transpose_wall<<<dim3(32, 32, 4), dim3(64, 4), 0, stream>>>(wq, wk, wv, wo, wqkvb, wob);

    gemm_bt<0><<<768, 512, 0, stream>>>(xb, wqkvb, Qb, Kb, Vtb, nullptr, cosb, sinb);
    attn_kernel<<<512, 512, 0, stream>>>(Qb, Kb, Vtb, AO);
    gemm_bt<1><<<256, 512, 0, stream>>>(AO, wob, nullptr, nullptr, nullptr, out, nullptr, nullptr);
}

// Round 6
// 537.885 us; speedup vs baseline: 1.3680x; 1.3680x over previous
//
#include <hip/hip_runtime.h>
#include <cstdint>
#include <cstddef>

typedef unsigned short u16;
using bf16x8  = __attribute__((ext_vector_type(8))) short;
using floatx4 = __attribute__((ext_vector_type(4))) float;

// ---------- helpers ----------
__device__ __forceinline__ u16 f2bf(float f) {
    union { float f; unsigned u; } v; v.f = f;
    unsigned r = v.u + 0x7fffu + ((v.u >> 16) & 1u);   // RNE
    return (u16)(r >> 16);
}
__device__ __forceinline__ float bf2f(u16 h) {
    union { unsigned u; float f; } v; v.u = ((unsigned)h) << 16; return v.f;
}
__device__ __forceinline__ floatx4 mfma16(bf16x8 a, bf16x8 b, floatx4 c) {
    return __builtin_amdgcn_mfma_f32_16x16x32_bf16(a, b, c, 0, 0, 0);
}
using gptr_t = const __attribute__((address_space(1))) unsigned int*;
using lptr_t = __attribute__((address_space(3))) unsigned int*;
__device__ __forceinline__ void lds16(const void* g, void* l) {
    __builtin_amdgcn_global_load_lds((gptr_t)g, (lptr_t)l, 16, 0, 0);
}
// Inline-asm ds_read_b128: invisible to SIInsertWaitcnts (no forced vmcnt(0) drain
// against outstanding global_load_lds). Ordering is ours: counted vmcnt + barriers.
typedef __attribute__((address_space(3))) const u16* lds_cp;
__device__ __forceinline__ bf16x8 dsr128(const u16* p) {
    bf16x8 r;
    asm volatile("ds_read_b128 %0, %1" : "=v"(r) : "v"((lds_cp)p));
    return r;
}

#define ATT_SCALE 0.1275758218522532f   // log2(e) / sqrt(128)

// ---------- 1. prep: transpose+convert 4 weights (z<4) and convert x (z==4), one launch ----------
__global__ __launch_bounds__(256) void prep(const float* __restrict__ x,
                                            const float* __restrict__ wq, const float* __restrict__ wk,
                                            const float* __restrict__ wv, const float* __restrict__ wo,
                                            u16* __restrict__ xb,
                                            u16* __restrict__ wqkvb, u16* __restrict__ wob) {
    const int z = blockIdx.z;
    const int tx = threadIdx.x, ty = threadIdx.y;   // (64,4)
    if (z < 4) {
        __shared__ float t[64][65];
        const float* in = (z == 0) ? wq : (z == 1) ? wk : (z == 2) ? wv : wo;
        u16* out = (z < 3) ? (wqkvb + (size_t)z * 2048 * 2048) : wob;
        int k0 = blockIdx.x * 64, n0 = blockIdx.y * 64;
#pragma unroll
        for (int i = 0; i < 16; ++i) {
            int r = i * 4 + ty;
            t[r][tx] = in[(size_t)(k0 + r) * 2048 + n0 + tx];
        }
        __syncthreads();
#pragma unroll
        for (int i = 0; i < 16; ++i) {
            int r = i * 4 + ty;
            out[(size_t)(n0 + r) * 2048 + k0 + tx] = f2bf(t[tx][r]);
        }
    } else {
        // cvt x: 16.78M floats, 1024 blocks x 256 thr x 16 float4 (grid-stride)
        const int flat = ty * 64 + tx;
        const size_t base = (size_t)(blockIdx.y * 32 + blockIdx.x) * 256 + flat;
        const size_t stride = 1024 * 256;
#pragma unroll
        for (int it = 0; it < 16; ++it) {
            size_t i = (base + it * stride) * 4;
            float4 v = *(const float4*)&x[i];
            ushort4 r; r.x = f2bf(v.x); r.y = f2bf(v.y); r.z = f2bf(v.z); r.w = f2bf(v.w);
            *(ushort4*)&xb[i] = r;
        }
    }
}

// ---------- 2. main GEMM: 256x256 tile, BK=64, 8 waves, 8-phase pipelined (T1..T5) ----------
// (unchanged: inline-asm ds_read + explicit waits, counted vmcnt(4) per K-tile,
//  rope-pair wave->column remap, fused RoPE epilogue on MODE 0.)
template <int MODE>
__global__ __launch_bounds__(512, 2) void gemm_bt(const u16* __restrict__ A, const u16* __restrict__ B,
                                                  u16* __restrict__ Qo, u16* __restrict__ Ko, u16* __restrict__ Vt,
                                                  float* __restrict__ Co,
                                                  const float* __restrict__ cosb, const float* __restrict__ sinb) {
    __shared__ __align__(16) u16 sA[2][16384];   // [buf][256 rows][64] 64 KiB
    __shared__ __align__(16) u16 sB[2][16384];   // 64 KiB -> 128 KiB total, 1 block/CU

    const int nbx = (MODE == 0) ? 24 : 8;
    const int bid = blockIdx.x;
    const int q8 = (int)gridDim.x >> 3;
    const int wg = (bid & 7) * q8 + (bid >> 3);
    const int bx = wg % nbx, by = wg / nbx;
    const int m0 = by << 8, n0 = bx << 8;

    const int tid = threadIdx.x;
    const int w = tid >> 6, lane = tid & 63;
    const int wm = w >> 2, wn = w & 3;              // 2 (M) x 4 (N) waves
    const int m16 = lane & 15, q4 = lane >> 4;
    const int lr = lane >> 3;
    const int lc8 = (lane & 7) ^ lr;                // pre-swizzled source chunk
    const int wnbase = (wn >> 1) * 128 + (wn & 1) * 32;   // rope-pair column base

    const u16* Ag = A + (size_t)(m0 + w * 16 + lr) * 2048 + lc8 * 8;
    const u16* Bg = B + (size_t)(n0 + w * 16 + lr) * 2048 + lc8 * 8;

    const int swz0 = ((q4 ^ (m16 & 7)) << 3);
    const int swz1 = (((4 + q4) ^ (m16 & 7)) << 3);

    floatx4 acc[8][4];
#pragma unroll
    for (int r = 0; r < 8; ++r)
#pragma unroll
        for (int c = 0; c < 4; ++c) acc[r][c] = (floatx4)0.0f;
    bf16x8 af[4][2];
    bf16x8 bf[4][2];

#define STAGE_A(b, h, t) do { \
    lds16(Ag + (size_t)((h) * 128) * 2048 + (t) * 64,     &sA[b][(h) * 8192 + w * 1024]);       \
    lds16(Ag + (size_t)((h) * 128 + 8) * 2048 + (t) * 64, &sA[b][(h) * 8192 + w * 1024 + 512]); \
} while (0)
#define STAGE_B(b, h, t) do { \
    lds16(Bg + (size_t)((h) * 128) * 2048 + (t) * 64,     &sB[b][(h) * 8192 + w * 1024]);       \
    lds16(Bg + (size_t)((h) * 128 + 8) * 2048 + (t) * 64, &sB[b][(h) * 8192 + w * 1024 + 512]); \
} while (0)
#define BAR() __builtin_amdgcn_s_barrier()
#define WAITL0() do { asm volatile("s_waitcnt lgkmcnt(0)" ::: "memory"); __builtin_amdgcn_sched_barrier(0); } while (0)
#define WAITL8() asm volatile("s_waitcnt lgkmcnt(8)" ::: "memory")
#define LDA_(cur, mq) do { _Pragma("unroll") for (int fr = 0; fr < 4; ++fr) { \
    const u16* p = &sA[cur][(wm * 128 + (mq) * 64 + fr * 16 + m16) * 64];      \
    af[fr][0] = dsr128(&p[swz0]);                                              \
    af[fr][1] = dsr128(&p[swz1]); } } while (0)
#define LDB_(cur, nq) do { _Pragma("unroll") for (int c = 0; c < 2; ++c) {     \
    const int j = (nq) * 2 + c;                                                \
    const u16* p = &sB[cur][(wnbase + (j & 1) * 16 + (j >> 1) * 64 + m16) * 64]; \
    bf[j][0] = dsr128(&p[swz0]);                                               \
    bf[j][1] = dsr128(&p[swz1]); } } while (0)
#define MM_(mq, nq) do { _Pragma("unroll") for (int kk = 0; kk < 2; ++kk)      \
    _Pragma("unroll") for (int fr = 0; fr < 4; ++fr)                           \
    _Pragma("unroll") for (int c = 0; c < 2; ++c)                              \
        acc[(mq) * 4 + fr][(nq) * 2 + c] =                                     \
            mfma16(af[fr][kk], bf[(nq) * 2 + c][kk], acc[(mq) * 4 + fr][(nq) * 2 + c]); } while (0)

    const int NT = 32;   // K = 2048 / BK = 64

    STAGE_B(0, 0, 0); STAGE_B(0, 1, 0);
    STAGE_A(0, 0, 0); STAGE_A(0, 1, 0);
    STAGE_B(1, 0, 1); STAGE_B(1, 1, 1);
    asm volatile("s_waitcnt vmcnt(4)" ::: "memory");
    __builtin_amdgcn_s_barrier();

#pragma unroll 2
    for (int t = 0; t < NT; ++t) {
        const int cur = t & 1;
        // ---- P0 ----
        LDB_(cur, 0);
        LDA_(cur, 0);
        if (t + 1 < NT) STAGE_A(cur ^ 1, 0, t + 1);
        WAITL8();
        BAR();
        WAITL0();
        __builtin_amdgcn_s_setprio(1); MM_(0, 0); __builtin_amdgcn_s_setprio(0);
        BAR();
        // ---- P1 ----
        LDB_(cur, 1);
        if (t + 1 < NT) STAGE_A(cur ^ 1, 1, t + 1);
        BAR();
        WAITL0();
        __builtin_amdgcn_s_setprio(1); MM_(0, 1); __builtin_amdgcn_s_setprio(0);
        BAR();
        // ---- P2 ----
        LDA_(cur, 1);
        if (t + 2 < NT) STAGE_B(cur, 0, t + 2);
        BAR();
        WAITL0();
        __builtin_amdgcn_s_setprio(1); MM_(1, 1); __builtin_amdgcn_s_setprio(0);
        BAR();
        // ---- P3 ----
        if (t + 2 < NT) STAGE_B(cur, 1, t + 2);
        BAR();
        __builtin_amdgcn_s_setprio(1); MM_(1, 0); __builtin_amdgcn_s_setprio(0);
        if (t + 2 < NT)      { asm volatile("s_waitcnt vmcnt(4)" ::: "memory"); }
        else if (t + 1 < NT) { asm volatile("s_waitcnt vmcnt(0)" ::: "memory"); }
        BAR();
    }

#undef STAGE_A
#undef STAGE_B
#undef BAR
#undef WAITL0
#undef WAITL8
#undef LDA_
#undef LDB_
#undef MM_

    if (MODE == 0) {
        const int which = n0 >> 11;           // 0=Q 1=K 2=V
        if (which < 2) {
            u16* dst = (which == 0) ? Qo : Ko;
            const float sc = (which == 0) ? ATT_SCALE : 1.0f;
            const int h = ((n0 >> 7) + (wn >> 1)) & 15;
            const int dp0 = (wn & 1) * 32 + m16;
#pragma unroll
            for (int fr = 0; fr < 8; ++fr) {
                const int mb = m0 + wm * 128 + fr * 16 + q4 * 4;
#pragma unroll
                for (int c0 = 0; c0 < 2; ++c0) {
                    const int dp = dp0 + c0 * 16;
#pragma unroll
                    for (int i = 0; i < 4; ++i) {
                        const int mm = mb + i;
                        const int b = mm >> 11, s = mm & 2047;
                        const float cs = cosb[(size_t)s * 64 + dp];
                        const float sn = sinb[(size_t)s * 64 + dp];
                        const float lo = acc[fr][c0][i], hi = acc[fr][c0 + 2][i];
                        const size_t base = ((size_t)((b * 16 + h) * 2048 + s) << 7) + dp;
                        dst[base]      = f2bf((lo * cs - hi * sn) * sc);
                        dst[base + 64] = f2bf((hi * cs + lo * sn) * sc);
                    }
                }
            }
        } else {
#pragma unroll
            for (int fr = 0; fr < 8; ++fr) {
                const int mb = m0 + wm * 128 + fr * 16 + q4 * 4;
                const int b = mb >> 11, s = mb & 2047;
#pragma unroll
                for (int c = 0; c < 4; ++c) {
                    const int n = n0 + wnbase + (c & 1) * 16 + (c >> 1) * 64 + m16;
                    const int h = (n >> 7) & 15, d = n & 127;
                    ushort4 pk;
                    pk.x = f2bf(acc[fr][c][0]); pk.y = f2bf(acc[fr][c][1]);
                    pk.z = f2bf(acc[fr][c][2]); pk.w = f2bf(acc[fr][c][3]);
                    *(ushort4*)&Vt[((size_t)((b * 16 + h) * 128 + d)) * 2048 + s] = pk;
                }
            }
        }
    } else {
#pragma unroll
        for (int fr = 0; fr < 8; ++fr) {
            const int mb = m0 + wm * 128 + fr * 16 + q4 * 4;
#pragma unroll
            for (int c = 0; c < 4; ++c) {
                const int n = n0 + wnbase + (c & 1) * 16 + (c >> 1) * 64 + m16;
#pragma unroll
                for (int i = 0; i < 4; ++i)
                    Co[(size_t)(mb + i) * 2048 + n] = acc[fr][c][i];
            }
        }
    }
}

// ---------- 3. flash attention (r4 structure restored): LDS-staged K/V with T14
// async-STAGE reg double-buffer, raw barriers; + wave-level fully-masked-tile skip
// + T13 defer-max (skip O-rescale when all row maxima grew < 2^8).
__global__ __launch_bounds__(512) void attn_kernel(const u16* __restrict__ Q, const u16* __restrict__ K,
                                                   const u16* __restrict__ VT, u16* __restrict__ AO) {
    __shared__ __align__(16) u16 ks[64 * 136];    // K-tile  [k 64][d 128+8]
    __shared__ __align__(16) u16 vts[128 * 72];   // V^T     [d 128][s 64+8]
    __shared__ __align__(16) u16 ps[256 * 72];    // P       [q 256][k 64+8]
    static const int iqmap[8] = {7, 6, 5, 4, 0, 1, 2, 3};  // (bx, bx+256) pairs balance
    const int bx = blockIdx.x;
    const int iq = iqmap[bx >> 6];
    const int bh = bx & 63;
    const int b = bh >> 4, h = bh & 15;
    const u16* Qg = Q  + (size_t)bh * (2048 * 128);
    const u16* Kg = K  + (size_t)bh * (2048 * 128);
    const u16* Vg = VT + (size_t)bh * (128 * 2048);
    const int tid = threadIdx.x, w = tid >> 6, lane = tid & 63;
    const int m16 = lane & 15, q4 = lane >> 4;
    const int jn = 4 * iq + 4;

    const int qrow = iq * 256 + w * 32;
    bf16x8 qf[2][4];
#pragma unroll
    for (int rm = 0; rm < 2; ++rm)
#pragma unroll
        for (int kk = 0; kk < 4; ++kk)
            qf[rm][kk] = *(const bf16x8*)&Qg[(size_t)(qrow + rm * 16 + m16) * 128 + kk * 32 + q4 * 8];

    floatx4 o[2][8];
#pragma unroll
    for (int rm = 0; rm < 2; ++rm)
#pragma unroll
        for (int c = 0; c < 8; ++c) o[rm][c] = (floatx4)0.0f;
    float mrow[2] = {-1e30f, -1e30f}, lrow[2] = {0.0f, 0.0f};

    const int kr0 = tid >> 4,          kc0 = tid & 15;
    const int kr1 = (512 + tid) >> 4,  kc1 = tid & 15;
    const int vr0 = tid >> 3,          vc0 = tid & 7;
    const int vr1 = (512 + tid) >> 3,  vc1 = tid & 7;
    uint4 kreg0, kreg1, vreg0, vreg1;

#define LOADKV(j) do { \
    kreg0 = *(const uint4*)&Kg[(size_t)((j) * 64 + kr0) * 128 + kc0 * 8]; \
    kreg1 = *(const uint4*)&Kg[(size_t)((j) * 64 + kr1) * 128 + kc1 * 8]; \
    vreg0 = *(const uint4*)&Vg[(size_t)vr0 * 2048 + (j) * 64 + vc0 * 8];  \
    vreg1 = *(const uint4*)&Vg[(size_t)vr1 * 2048 + (j) * 64 + vc1 * 8];  \
} while (0)

    LOADKV(0);

    for (int j = 0; j < jn; ++j) {
        // staging + barriers are unconditional (all 8 waves), compute may be skipped
        asm volatile("" ::: "memory");
        __builtin_amdgcn_s_barrier();
        asm volatile("" ::: "memory");
        *(uint4*)&ks[kr0 * 136 + kc0 * 8] = kreg0;
        *(uint4*)&ks[kr1 * 136 + kc1 * 8] = kreg1;
        *(uint4*)&vts[vr0 * 72 + vc0 * 8] = vreg0;
        *(uint4*)&vts[vr1 * 72 + vc1 * 8] = vreg1;
        if (j + 1 < jn) LOADKV(j + 1);
        asm volatile("s_waitcnt lgkmcnt(0)" ::: "memory");
        __builtin_amdgcn_s_barrier();
        asm volatile("" ::: "memory");

        // wave-level skip: tile fully masked for this wave's 32 q-rows -> contributes 0
        if (j * 64 > qrow + 31) continue;

        floatx4 sacc[2][4];
#pragma unroll
        for (int rm = 0; rm < 2; ++rm)
#pragma unroll
            for (int r = 0; r < 4; ++r) sacc[rm][r] = (floatx4)0.0f;
        __builtin_amdgcn_s_setprio(1);
#pragma unroll
        for (int kk = 0; kk < 4; ++kk) {
            bf16x8 kb[4];
#pragma unroll
            for (int r = 0; r < 4; ++r)
                kb[r] = *(const bf16x8*)&ks[(r * 16 + m16) * 136 + kk * 32 + q4 * 8];
#pragma unroll
            for (int rm = 0; rm < 2; ++rm)
#pragma unroll
                for (int r = 0; r < 4; ++r)
                    sacc[rm][r] = mfma16(kb[r], qf[rm][kk], sacc[rm][r]);
        }
        __builtin_amdgcn_s_setprio(0);

        if (j >= 4 * iq) {
#pragma unroll
            for (int rm = 0; rm < 2; ++rm) {
                const int qg = qrow + rm * 16 + m16;
#pragma unroll
                for (int r = 0; r < 4; ++r)
#pragma unroll
                    for (int i = 0; i < 4; ++i) {
                        int kg = j * 64 + r * 16 + q4 * 4 + i;
                        if (kg > qg) sacc[rm][r][i] = -1e30f;
                    }
            }
        }

#pragma unroll
        for (int rm = 0; rm < 2; ++rm) {
            float pmax = -1e30f;
#pragma unroll
            for (int r = 0; r < 4; ++r)
#pragma unroll
                for (int i = 0; i < 4; ++i) pmax = fmaxf(pmax, sacc[rm][r][i]);
            pmax = fmaxf(pmax, __shfl_xor(pmax, 16));
            pmax = fmaxf(pmax, __shfl_xor(pmax, 32));
            // T13 defer-max: rescale only if some row's max grew by > 8 (exp2 domain).
            // P then bounded by 2^8; bf16/f32 headroom is ample. First tile: mrow=-1e30
            // forces the rescale path (alpha = exp2(-inf) = 0).
            if (__any(pmax - mrow[rm] > 8.0f)) {
                float mnew = fmaxf(mrow[rm], pmax);
                float alpha = __builtin_amdgcn_exp2f(mrow[rm] - mnew);
                mrow[rm] = mnew;
                lrow[rm] *= alpha;
                float abc[4];
#pragma unroll
                for (int i = 0; i < 4; ++i) abc[i] = __shfl(alpha, q4 * 4 + i);
#pragma unroll
                for (int c = 0; c < 8; ++c)
#pragma unroll
                    for (int i = 0; i < 4; ++i) o[rm][c][i] *= abc[i];
            }

            float psum = 0.0f;
#pragma unroll
            for (int r = 0; r < 4; ++r) {
                float p0 = __builtin_amdgcn_exp2f(sacc[rm][r][0] - mrow[rm]);
                float p1 = __builtin_amdgcn_exp2f(sacc[rm][r][1] - mrow[rm]);
                float p2 = __builtin_amdgcn_exp2f(sacc[rm][r][2] - mrow[rm]);
                float p3 = __builtin_amdgcn_exp2f(sacc[rm][r][3] - mrow[rm]);
                psum += (p0 + p1) + (p2 + p3);
                ushort4 pk; pk.x = f2bf(p0); pk.y = f2bf(p1); pk.z = f2bf(p2); pk.w = f2bf(p3);
                *(ushort4*)&ps[(w * 32 + rm * 16 + m16) * 72 + r * 16 + q4 * 4] = pk;
            }
            psum += __shfl_xor(psum, 16);
            psum += __shfl_xor(psum, 32);
            lrow[rm] += psum;
        }

#pragma unroll
        for (int kk = 0; kk < 2; ++kk) {
            bf16x8 pa[2];
#pragma unroll
            for (int rm = 0; rm < 2; ++rm)
                pa[rm] = *(const bf16x8*)&ps[(w * 32 + rm * 16 + m16) * 72 + kk * 32 + q4 * 8];
            __builtin_amdgcn_s_setprio(1);
#pragma unroll
            for (int ch = 0; ch < 2; ++ch) {
                bf16x8 vb[4];
#pragma unroll
                for (int c = 0; c < 4; ++c)
                    vb[c] = *(const bf16x8*)&vts[((ch * 4 + c) * 16 + m16) * 72 + kk * 32 + q4 * 8];
#pragma unroll
                for (int rm = 0; rm < 2; ++rm)
#pragma unroll
                    for (int c = 0; c < 4; ++c)
                        o[rm][ch * 4 + c] = mfma16(pa[rm], vb[c], o[rm][ch * 4 + c]);
            }
            __builtin_amdgcn_s_setprio(0);
        }
    }
#undef LOADKV

#pragma unroll
    for (int rm = 0; rm < 2; ++rm) {
        float linv = __builtin_amdgcn_rcpf(lrow[rm]);
        float li[4];
#pragma unroll
        for (int i = 0; i < 4; ++i) li[i] = __shfl(linv, q4 * 4 + i);
#pragma unroll
        for (int c = 0; c < 8; ++c)
#pragma unroll
            for (int i = 0; i < 4; ++i) {
                int s = qrow + rm * 16 + q4 * 4 + i;
                int d = c * 16 + m16;
                AO[((size_t)(b * 2048 + s)) * 2048 + h * 128 + d] = f2bf(o[rm][c][i] * li[i]);
            }
    }
}

// ---------- launch ----------
extern "C" void kernel_launch(void* const* d_in, const int* in_sizes, int n_in,
                              void* d_out, int out_size, void* d_ws, size_t ws_size,
                              hipStream_t stream) {
    const float* x    = (const float*)d_in[0];
    const float* wq   = (const float*)d_in[1];
    const float* wk   = (const float*)d_in[2];
    const float* wv   = (const float*)d_in[3];
    const float* wo   = (const float*)d_in[4];
    const float* cosb = (const float*)d_in[5];
    const float* sinb = (const float*)d_in[6];
    float* out = (float*)d_out;

    char* ws = (char*)d_ws;
    u16* xb    = (u16*)(ws);                          // 32 MiB
    u16* AO    = xb;                                  // alias: xb dead after QKV GEMM
    u16* wqkvb = (u16*)(ws + 33554432);               // 24 MiB
    u16* wob   = (u16*)(ws + 58720256);               // 8 MiB
    u16* Qb    = (u16*)(ws + 67108864);               // 32 MiB
    u16* Kb    = (u16*)(ws + 100663296);              // 32 MiB
    u16* Vtb   = (u16*)(ws + 134217728);              // 32 MiB (V stored transposed)

    prep<<<dim3(32, 32, 5), dim3(64, 4), 0, stream>>>(x, wq, wk, wv, wo, xb, wqkvb, wob);

    gemm_bt<0><<<768, 512, 0, stream>>>(xb, wqkvb, Qb, Kb, Vtb, nullptr, cosb, sinb);
    attn_kernel<<<512, 512, 0, stream>>>(Qb, Kb, Vtb, AO);
    gemm_bt<1><<<256, 512, 0, stream>>>(AO, wob, nullptr, nullptr, nullptr, out, nullptr, nullptr);
}

// Round 7
// 536.965 us; speedup vs baseline: 1.3703x; 1.0017x over previous
//
#include <hip/hip_runtime.h>
#include <cstdint>
#include <cstddef>

typedef unsigned short u16;
using bf16x8  = __attribute__((ext_vector_type(8))) short;
using floatx4 = __attribute__((ext_vector_type(4))) float;

// ---------- helpers ----------
__device__ __forceinline__ u16 f2bf(float f) {
    union { float f; unsigned u; } v; v.f = f;
    unsigned r = v.u + 0x7fffu + ((v.u >> 16) & 1u);   // RNE
    return (u16)(r >> 16);
}
__device__ __forceinline__ float bf2f(u16 h) {
    union { unsigned u; float f; } v; v.u = ((unsigned)h) << 16; return v.f;
}
__device__ __forceinline__ floatx4 mfma16(bf16x8 a, bf16x8 b, floatx4 c) {
    return __builtin_amdgcn_mfma_f32_16x16x32_bf16(a, b, c, 0, 0, 0);
}
using gptr_t = const __attribute__((address_space(1))) unsigned int*;
using lptr_t = __attribute__((address_space(3))) unsigned int*;
__device__ __forceinline__ void lds16(const void* g, void* l) {
    __builtin_amdgcn_global_load_lds((gptr_t)g, (lptr_t)l, 16, 0, 0);
}
// Inline-asm ds_read_b128: invisible to SIInsertWaitcnts (no forced vmcnt(0) drain
// against outstanding global_load_lds). Ordering is ours: counted vmcnt + barriers.
typedef __attribute__((address_space(3))) const u16* lds_cp;
__device__ __forceinline__ bf16x8 dsr128(const u16* p) {
    bf16x8 r;
    asm volatile("ds_read_b128 %0, %1" : "=v"(r) : "v"((lds_cp)p));
    return r;
}

#define ATT_SCALE 0.1275758218522532f   // log2(e) / sqrt(128)

// ---------- 1. prep: transpose+convert 4 weights (z<4) and convert x (z==4), one launch ----------
__global__ __launch_bounds__(256) void prep(const float* __restrict__ x,
                                            const float* __restrict__ wq, const float* __restrict__ wk,
                                            const float* __restrict__ wv, const float* __restrict__ wo,
                                            u16* __restrict__ xb,
                                            u16* __restrict__ wqkvb, u16* __restrict__ wob) {
    const int z = blockIdx.z;
    const int tx = threadIdx.x, ty = threadIdx.y;   // (64,4)
    if (z < 4) {
        __shared__ float t[64][65];
        const float* in = (z == 0) ? wq : (z == 1) ? wk : (z == 2) ? wv : wo;
        u16* out = (z < 3) ? (wqkvb + (size_t)z * 2048 * 2048) : wob;
        int k0 = blockIdx.x * 64, n0 = blockIdx.y * 64;
#pragma unroll
        for (int i = 0; i < 16; ++i) {
            int r = i * 4 + ty;
            t[r][tx] = in[(size_t)(k0 + r) * 2048 + n0 + tx];
        }
        __syncthreads();
#pragma unroll
        for (int i = 0; i < 16; ++i) {
            int r = i * 4 + ty;
            out[(size_t)(n0 + r) * 2048 + k0 + tx] = f2bf(t[tx][r]);
        }
    } else {
        // cvt x: 16.78M floats, 1024 blocks x 256 thr x 16 float4 (grid-stride)
        const int flat = ty * 64 + tx;
        const size_t base = (size_t)(blockIdx.y * 32 + blockIdx.x) * 256 + flat;
        const size_t stride = 1024 * 256;
#pragma unroll
        for (int it = 0; it < 16; ++it) {
            size_t i = (base + it * stride) * 4;
            float4 v = *(const float4*)&x[i];
            ushort4 r; r.x = f2bf(v.x); r.y = f2bf(v.y); r.z = f2bf(v.z); r.w = f2bf(v.w);
            *(ushort4*)&xb[i] = r;
        }
    }
}

// ---------- 2. main GEMM: 256x256 tile, BK=64, 8 waves, 8-phase pipelined (T1..T5) ----------
// (unchanged: inline-asm ds_read + explicit waits, counted vmcnt(4) per K-tile,
//  rope-pair wave->column remap, fused RoPE epilogue on MODE 0.)
template <int MODE>
__global__ __launch_bounds__(512, 2) void gemm_bt(const u16* __restrict__ A, const u16* __restrict__ B,
                                                  u16* __restrict__ Qo, u16* __restrict__ Ko, u16* __restrict__ Vt,
                                                  float* __restrict__ Co,
                                                  const float* __restrict__ cosb, const float* __restrict__ sinb) {
    __shared__ __align__(16) u16 sA[2][16384];   // [buf][256 rows][64] 64 KiB
    __shared__ __align__(16) u16 sB[2][16384];   // 64 KiB -> 128 KiB total, 1 block/CU

    const int nbx = (MODE == 0) ? 24 : 8;
    const int bid = blockIdx.x;
    const int q8 = (int)gridDim.x >> 3;
    const int wg = (bid & 7) * q8 + (bid >> 3);
    const int bx = wg % nbx, by = wg / nbx;
    const int m0 = by << 8, n0 = bx << 8;

    const int tid = threadIdx.x;
    const int w = tid >> 6, lane = tid & 63;
    const int wm = w >> 2, wn = w & 3;              // 2 (M) x 4 (N) waves
    const int m16 = lane & 15, q4 = lane >> 4;
    const int lr = lane >> 3;
    const int lc8 = (lane & 7) ^ lr;                // pre-swizzled source chunk
    const int wnbase = (wn >> 1) * 128 + (wn & 1) * 32;   // rope-pair column base

    const u16* Ag = A + (size_t)(m0 + w * 16 + lr) * 2048 + lc8 * 8;
    const u16* Bg = B + (size_t)(n0 + w * 16 + lr) * 2048 + lc8 * 8;

    const int swz0 = ((q4 ^ (m16 & 7)) << 3);
    const int swz1 = (((4 + q4) ^ (m16 & 7)) << 3);

    floatx4 acc[8][4];
#pragma unroll
    for (int r = 0; r < 8; ++r)
#pragma unroll
        for (int c = 0; c < 4; ++c) acc[r][c] = (floatx4)0.0f;
    bf16x8 af[4][2];
    bf16x8 bf[4][2];

#define STAGE_A(b, h, t) do { \
    lds16(Ag + (size_t)((h) * 128) * 2048 + (t) * 64,     &sA[b][(h) * 8192 + w * 1024]);       \
    lds16(Ag + (size_t)((h) * 128 + 8) * 2048 + (t) * 64, &sA[b][(h) * 8192 + w * 1024 + 512]); \
} while (0)
#define STAGE_B(b, h, t) do { \
    lds16(Bg + (size_t)((h) * 128) * 2048 + (t) * 64,     &sB[b][(h) * 8192 + w * 1024]);       \
    lds16(Bg + (size_t)((h) * 128 + 8) * 2048 + (t) * 64, &sB[b][(h) * 8192 + w * 1024 + 512]); \
} while (0)
#define BAR() __builtin_amdgcn_s_barrier()
#define WAITL0() do { asm volatile("s_waitcnt lgkmcnt(0)" ::: "memory"); __builtin_amdgcn_sched_barrier(0); } while (0)
#define WAITL8() asm volatile("s_waitcnt lgkmcnt(8)" ::: "memory")
#define LDA_(cur, mq) do { _Pragma("unroll") for (int fr = 0; fr < 4; ++fr) { \
    const u16* p = &sA[cur][(wm * 128 + (mq) * 64 + fr * 16 + m16) * 64];      \
    af[fr][0] = dsr128(&p[swz0]);                                              \
    af[fr][1] = dsr128(&p[swz1]); } } while (0)
#define LDB_(cur, nq) do { _Pragma("unroll") for (int c = 0; c < 2; ++c) {     \
    const int j = (nq) * 2 + c;                                                \
    const u16* p = &sB[cur][(wnbase + (j & 1) * 16 + (j >> 1) * 64 + m16) * 64]; \
    bf[j][0] = dsr128(&p[swz0]);                                               \
    bf[j][1] = dsr128(&p[swz1]); } } while (0)
#define MM_(mq, nq) do { _Pragma("unroll") for (int kk = 0; kk < 2; ++kk)      \
    _Pragma("unroll") for (int fr = 0; fr < 4; ++fr)                           \
    _Pragma("unroll") for (int c = 0; c < 2; ++c)                              \
        acc[(mq) * 4 + fr][(nq) * 2 + c] =                                     \
            mfma16(af[fr][kk], bf[(nq) * 2 + c][kk], acc[(mq) * 4 + fr][(nq) * 2 + c]); } while (0)

    const int NT = 32;   // K = 2048 / BK = 64

    STAGE_B(0, 0, 0); STAGE_B(0, 1, 0);
    STAGE_A(0, 0, 0); STAGE_A(0, 1, 0);
    STAGE_B(1, 0, 1); STAGE_B(1, 1, 1);
    asm volatile("s_waitcnt vmcnt(4)" ::: "memory");
    __builtin_amdgcn_s_barrier();

#pragma unroll 2
    for (int t = 0; t < NT; ++t) {
        const int cur = t & 1;
        // ---- P0 ----
        LDB_(cur, 0);
        LDA_(cur, 0);
        if (t + 1 < NT) STAGE_A(cur ^ 1, 0, t + 1);
        WAITL8();
        BAR();
        WAITL0();
        __builtin_amdgcn_s_setprio(1); MM_(0, 0); __builtin_amdgcn_s_setprio(0);
        BAR();
        // ---- P1 ----
        LDB_(cur, 1);
        if (t + 1 < NT) STAGE_A(cur ^ 1, 1, t + 1);
        BAR();
        WAITL0();
        __builtin_amdgcn_s_setprio(1); MM_(0, 1); __builtin_amdgcn_s_setprio(0);
        BAR();
        // ---- P2 ----
        LDA_(cur, 1);
        if (t + 2 < NT) STAGE_B(cur, 0, t + 2);
        BAR();
        WAITL0();
        __builtin_amdgcn_s_setprio(1); MM_(1, 1); __builtin_amdgcn_s_setprio(0);
        BAR();
        // ---- P3 ----
        if (t + 2 < NT) STAGE_B(cur, 1, t + 2);
        BAR();
        __builtin_amdgcn_s_setprio(1); MM_(1, 0); __builtin_amdgcn_s_setprio(0);
        if (t + 2 < NT)      { asm volatile("s_waitcnt vmcnt(4)" ::: "memory"); }
        else if (t + 1 < NT) { asm volatile("s_waitcnt vmcnt(0)" ::: "memory"); }
        BAR();
    }

#undef STAGE_A
#undef STAGE_B
#undef BAR
#undef WAITL0
#undef WAITL8
#undef LDA_
#undef LDB_
#undef MM_

    if (MODE == 0) {
        const int which = n0 >> 11;           // 0=Q 1=K 2=V
        if (which < 2) {
            u16* dst = (which == 0) ? Qo : Ko;
            const float sc = (which == 0) ? ATT_SCALE : 1.0f;
            const int h = ((n0 >> 7) + (wn >> 1)) & 15;
            const int dp0 = (wn & 1) * 32 + m16;
#pragma unroll
            for (int fr = 0; fr < 8; ++fr) {
                const int mb = m0 + wm * 128 + fr * 16 + q4 * 4;
#pragma unroll
                for (int c0 = 0; c0 < 2; ++c0) {
                    const int dp = dp0 + c0 * 16;
#pragma unroll
                    for (int i = 0; i < 4; ++i) {
                        const int mm = mb + i;
                        const int b = mm >> 11, s = mm & 2047;
                        const float cs = cosb[(size_t)s * 64 + dp];
                        const float sn = sinb[(size_t)s * 64 + dp];
                        const float lo = acc[fr][c0][i], hi = acc[fr][c0 + 2][i];
                        const size_t base = ((size_t)((b * 16 + h) * 2048 + s) << 7) + dp;
                        dst[base]      = f2bf((lo * cs - hi * sn) * sc);
                        dst[base + 64] = f2bf((hi * cs + lo * sn) * sc);
                    }
                }
            }
        } else {
#pragma unroll
            for (int fr = 0; fr < 8; ++fr) {
                const int mb = m0 + wm * 128 + fr * 16 + q4 * 4;
                const int b = mb >> 11, s = mb & 2047;
#pragma unroll
                for (int c = 0; c < 4; ++c) {
                    const int n = n0 + wnbase + (c & 1) * 16 + (c >> 1) * 64 + m16;
                    const int h = (n >> 7) & 15, d = n & 127;
                    ushort4 pk;
                    pk.x = f2bf(acc[fr][c][0]); pk.y = f2bf(acc[fr][c][1]);
                    pk.z = f2bf(acc[fr][c][2]); pk.w = f2bf(acc[fr][c][3]);
                    *(ushort4*)&Vt[((size_t)((b * 16 + h) * 128 + d)) * 2048 + s] = pk;
                }
            }
        }
    } else {
#pragma unroll
        for (int fr = 0; fr < 8; ++fr) {
            const int mb = m0 + wm * 128 + fr * 16 + q4 * 4;
#pragma unroll
            for (int c = 0; c < 4; ++c) {
                const int n = n0 + wnbase + (c & 1) * 16 + (c >> 1) * 64 + m16;
#pragma unroll
                for (int i = 0; i < 4; ++i)
                    Co[(size_t)(mb + i) * 2048 + n] = acc[fr][c][i];
            }
        }
    }
}

// ---------- 3. flash attention: LDS-staged K/V (T14 async-STAGE), chunk-XOR swizzled
// LDS (GEMM-proven pattern -> 0 bank conflicts), masked-tile skip, T13 defer-max.
// Swizzle: 16B-chunk index XOR'd with (row&7) on BOTH write and read (rule #21).
//   ks  [64 rows][128 u16]: chunk = col16 (16/row), key = row&7
//   vts [128 rows][64 u16]: chunk = col16 (8/row),  key = row&7
//   ps  [256 rows][64 u16]: byte-level XOR ((row&7)<<4) on col offsets (8B writes, 16B reads)
__global__ __launch_bounds__(512) void attn_kernel(const u16* __restrict__ Q, const u16* __restrict__ K,
                                                   const u16* __restrict__ VT, u16* __restrict__ AO) {
    __shared__ __align__(16) u16 ks[64 * 128];    // 16 KiB
    __shared__ __align__(16) u16 vts[128 * 64];   // 16 KiB
    __shared__ __align__(16) u16 ps[256 * 64];    // 32 KiB
    static const int iqmap[8] = {7, 6, 5, 4, 0, 1, 2, 3};  // (bx, bx+256) pairs balance
    const int bx = blockIdx.x;
    const int iq = iqmap[bx >> 6];
    const int bh = bx & 63;
    const int b = bh >> 4, h = bh & 15;
    const u16* Qg = Q  + (size_t)bh * (2048 * 128);
    const u16* Kg = K  + (size_t)bh * (2048 * 128);
    const u16* Vg = VT + (size_t)bh * (128 * 2048);
    const int tid = threadIdx.x, w = tid >> 6, lane = tid & 63;
    const int m16 = lane & 15, q4 = lane >> 4;
    const int jn = 4 * iq + 4;
    const int key = m16 & 7;                      // read-side swizzle key (row&7 == m16&7)

    const int qrow = iq * 256 + w * 32;
    bf16x8 qf[2][4];
#pragma unroll
    for (int rm = 0; rm < 2; ++rm)
#pragma unroll
        for (int kk = 0; kk < 4; ++kk)
            qf[rm][kk] = *(const bf16x8*)&Qg[(size_t)(qrow + rm * 16 + m16) * 128 + kk * 32 + q4 * 8];

    floatx4 o[2][8];
#pragma unroll
    for (int rm = 0; rm < 2; ++rm)
#pragma unroll
        for (int c = 0; c < 8; ++c) o[rm][c] = (floatx4)0.0f;
    float mrow[2] = {-1e30f, -1e30f}, lrow[2] = {0.0f, 0.0f};

    const int kr0 = tid >> 4,          kc0 = tid & 15;
    const int kr1 = (512 + tid) >> 4,  kc1 = tid & 15;
    const int vr0 = tid >> 3,          vc0 = tid & 7;
    const int vr1 = (512 + tid) >> 3,  vc1 = tid & 7;
    uint4 kreg0, kreg1, vreg0, vreg1;

#define LOADKV(j) do { \
    kreg0 = *(const uint4*)&Kg[(size_t)((j) * 64 + kr0) * 128 + kc0 * 8]; \
    kreg1 = *(const uint4*)&Kg[(size_t)((j) * 64 + kr1) * 128 + kc1 * 8]; \
    vreg0 = *(const uint4*)&Vg[(size_t)vr0 * 2048 + (j) * 64 + vc0 * 8];  \
    vreg1 = *(const uint4*)&Vg[(size_t)vr1 * 2048 + (j) * 64 + vc1 * 8];  \
} while (0)

    LOADKV(0);

    for (int j = 0; j < jn; ++j) {
        // staging + barriers are unconditional (all 8 waves), compute may be skipped
        asm volatile("" ::: "memory");
        __builtin_amdgcn_s_barrier();
        asm volatile("" ::: "memory");
        *(uint4*)&ks[kr0 * 128 + ((kc0 ^ (kr0 & 7)) * 8)] = kreg0;
        *(uint4*)&ks[kr1 * 128 + ((kc1 ^ (kr1 & 7)) * 8)] = kreg1;
        *(uint4*)&vts[vr0 * 64 + ((vc0 ^ (vr0 & 7)) * 8)] = vreg0;
        *(uint4*)&vts[vr1 * 64 + ((vc1 ^ (vr1 & 7)) * 8)] = vreg1;
        if (j + 1 < jn) LOADKV(j + 1);
        asm volatile("s_waitcnt lgkmcnt(0)" ::: "memory");
        __builtin_amdgcn_s_barrier();
        asm volatile("" ::: "memory");

        // wave-level skip: tile fully masked for this wave's 32 q-rows -> contributes 0
        if (j * 64 > qrow + 31) continue;

        floatx4 sacc[2][4];
#pragma unroll
        for (int rm = 0; rm < 2; ++rm)
#pragma unroll
            for (int r = 0; r < 4; ++r) sacc[rm][r] = (floatx4)0.0f;
        __builtin_amdgcn_s_setprio(1);
#pragma unroll
        for (int kk = 0; kk < 4; ++kk) {
            bf16x8 kb[4];
#pragma unroll
            for (int r = 0; r < 4; ++r)
                kb[r] = *(const bf16x8*)&ks[(r * 16 + m16) * 128 + (((kk * 4 + q4) ^ key) * 8)];
#pragma unroll
            for (int rm = 0; rm < 2; ++rm)
#pragma unroll
                for (int r = 0; r < 4; ++r)
                    sacc[rm][r] = mfma16(kb[r], qf[rm][kk], sacc[rm][r]);
        }
        __builtin_amdgcn_s_setprio(0);

        if (j >= 4 * iq) {
#pragma unroll
            for (int rm = 0; rm < 2; ++rm) {
                const int qg = qrow + rm * 16 + m16;
#pragma unroll
                for (int r = 0; r < 4; ++r)
#pragma unroll
                    for (int i = 0; i < 4; ++i) {
                        int kg = j * 64 + r * 16 + q4 * 4 + i;
                        if (kg > qg) sacc[rm][r][i] = -1e30f;
                    }
            }
        }

#pragma unroll
        for (int rm = 0; rm < 2; ++rm) {
            float pmax = -1e30f;
#pragma unroll
            for (int r = 0; r < 4; ++r)
#pragma unroll
                for (int i = 0; i < 4; ++i) pmax = fmaxf(pmax, sacc[rm][r][i]);
            pmax = fmaxf(pmax, __shfl_xor(pmax, 16));
            pmax = fmaxf(pmax, __shfl_xor(pmax, 32));
            // T13 defer-max: rescale only if some row's max grew by > 8 (exp2 domain).
            if (__any(pmax - mrow[rm] > 8.0f)) {
                float mnew = fmaxf(mrow[rm], pmax);
                float alpha = __builtin_amdgcn_exp2f(mrow[rm] - mnew);
                mrow[rm] = mnew;
                lrow[rm] *= alpha;
                float abc[4];
#pragma unroll
                for (int i = 0; i < 4; ++i) abc[i] = __shfl(alpha, q4 * 4 + i);
#pragma unroll
                for (int c = 0; c < 8; ++c)
#pragma unroll
                    for (int i = 0; i < 4; ++i) o[rm][c][i] *= abc[i];
            }

            float psum = 0.0f;
            const int prow = (w * 32 + rm * 16 + m16) * 64;
#pragma unroll
            for (int r = 0; r < 4; ++r) {
                float p0 = __builtin_amdgcn_exp2f(sacc[rm][r][0] - mrow[rm]);
                float p1 = __builtin_amdgcn_exp2f(sacc[rm][r][1] - mrow[rm]);
                float p2 = __builtin_amdgcn_exp2f(sacc[rm][r][2] - mrow[rm]);
                float p3 = __builtin_amdgcn_exp2f(sacc[rm][r][3] - mrow[rm]);
                psum += (p0 + p1) + (p2 + p3);
                ushort4 pk; pk.x = f2bf(p0); pk.y = f2bf(p1); pk.z = f2bf(p2); pk.w = f2bf(p3);
                *(ushort4*)&ps[prow + ((r * 16 + q4 * 4) ^ (key << 3))] = pk;
            }
            psum += __shfl_xor(psum, 16);
            psum += __shfl_xor(psum, 32);
            lrow[rm] += psum;
        }

#pragma unroll
        for (int kk = 0; kk < 2; ++kk) {
            bf16x8 pa[2];
#pragma unroll
            for (int rm = 0; rm < 2; ++rm)
                pa[rm] = *(const bf16x8*)&ps[(w * 32 + rm * 16 + m16) * 64 + ((kk * 32 + q4 * 8) ^ (key << 3))];
            __builtin_amdgcn_s_setprio(1);
#pragma unroll
            for (int ch = 0; ch < 2; ++ch) {
                bf16x8 vb[4];
#pragma unroll
                for (int c = 0; c < 4; ++c)
                    vb[c] = *(const bf16x8*)&vts[((ch * 4 + c) * 16 + m16) * 64 + (((kk * 4 + q4) ^ key) * 8)];
#pragma unroll
                for (int rm = 0; rm < 2; ++rm)
#pragma unroll
                    for (int c = 0; c < 4; ++c)
                        o[rm][ch * 4 + c] = mfma16(pa[rm], vb[c], o[rm][ch * 4 + c]);
            }
            __builtin_amdgcn_s_setprio(0);
        }
    }
#undef LOADKV

#pragma unroll
    for (int rm = 0; rm < 2; ++rm) {
        float linv = __builtin_amdgcn_rcpf(lrow[rm]);
        float li[4];
#pragma unroll
        for (int i = 0; i < 4; ++i) li[i] = __shfl(linv, q4 * 4 + i);
#pragma unroll
        for (int c = 0; c < 8; ++c)
#pragma unroll
            for (int i = 0; i < 4; ++i) {
                int s = qrow + rm * 16 + q4 * 4 + i;
                int d = c * 16 + m16;
                AO[((size_t)(b * 2048 + s)) * 2048 + h * 128 + d] = f2bf(o[rm][c][i] * li[i]);
            }
    }
}

// ---------- launch ----------
extern "C" void kernel_launch(void* const* d_in, const int* in_sizes, int n_in,
                              void* d_out, int out_size, void* d_ws, size_t ws_size,
                              hipStream_t stream) {
    const float* x    = (const float*)d_in[0];
    const float* wq   = (const float*)d_in[1];
    const float* wk   = (const float*)d_in[2];
    const float* wv   = (const float*)d_in[3];
    const float* wo   = (const float*)d_in[4];
    const float* cosb = (const float*)d_in[5];
    const float* sinb = (const float*)d_in[6];
    float* out = (float*)d_out;

    char* ws = (char*)d_ws;
    u16* xb    = (u16*)(ws);                          // 32 MiB
    u16* AO    = xb;                                  // alias: xb dead after QKV GEMM
    u16* wqkvb = (u16*)(ws + 33554432);               // 24 MiB
    u16* wob   = (u16*)(ws + 58720256);               // 8 MiB
    u16* Qb    = (u16*)(ws + 67108864);               // 32 MiB
    u16* Kb    = (u16*)(ws + 100663296);              // 32 MiB
    u16* Vtb   = (u16*)(ws + 134217728);              // 32 MiB (V stored transposed)

    prep<<<dim3(32, 32, 5), dim3(64, 4), 0, stream>>>(x, wq, wk, wv, wo, xb, wqkvb, wob);

    gemm_bt<0><<<768, 512, 0, stream>>>(xb, wqkvb, Qb, Kb, Vtb, nullptr, cosb, sinb);
    attn_kernel<<<512, 512, 0, stream>>>(Qb, Kb, Vtb, AO);
    gemm_bt<1><<<256, 512, 0, stream>>>(AO, wob, nullptr, nullptr, nullptr, out, nullptr, nullptr);
}